// Round 17
// baseline (265.659 us; speedup 1.0000x reference)
//
#include <hip/hip_runtime.h>
#include <cstdint>

// inter_prediction: fused point-cloud edge-conv on MI355X (gfx950).
// Inputs (setup_inputs order):
//  0 xyz [1,N,3] f32 | 1 xyz_nn [1,N,3] f32 | 2 points [1,N,64] f32
//  3 knn [1,N,16] i32 | 4 dists [1,N,16] f32 | 5 mask [1,N,16] bool (layout
//  runtime-detected int32-vs-byte) | 6..15 weights/biases f32.
// Output: concat(xyz.flat [3N], out.flat [64N]) f32
//
// MFMA mappings (verified learn_hip m89/m91): 16x16x32_f16 A: row=lane&15,
// k=(lane>>4)*8+e. B: col=lane&15, k=(lane>>4)*8+e. C/D: col=lane&15,
// row=(lane>>4)*4+reg. 16x16x16f16: k=(lane>>4)*4+j -> a D-fragment IS a
// valid K=16 B-fragment (ones-row MFMA gives per-column sums, no shuffles).
//
// R17: two fixes on R16 (112.5us):
// (a) __launch_bounds__ 2nd arg is waves/EU: (512,4) capped the edge at
//     2 blocks/CU = 16 waves (matches measured ~32% all along). (512,6)
//     -> 3 blocks/CU = 24 waves; VGPR budget 512/6~85 >= our 64, so no
//     spill expected (R14's (512,8) forced 32 VGPR and spilled).
// (b) point_kernel still had the scattered weight prologue R16 removed
//     from edge. prep now also builds point tables (Wm1t/Wm2t/Wsct/bias,
//     32KB fp16) and is folded into cvt_kernel (blocks 0/1) — one less
//     launch; point prologue becomes a contiguous half8 copy.

namespace {

typedef _Float16 half8  __attribute__((ext_vector_type(8)));
typedef _Float16 half4v __attribute__((ext_vector_type(4)));
typedef _Float16 half2v __attribute__((ext_vector_type(2)));
typedef float    f32x4  __attribute__((ext_vector_type(4)));

template <int I> struct IC { static constexpr int value = I; };

constexpr int K   = 16;
constexpr int CIN = 64;
constexpr int CG  = 68;   // 4 + CIN
constexpr int HID = 32;
constexpr int MH  = 64;

constexpr int X_LD   = 104;  // point_kernel Wm1 stride
constexpr int AGG_LD = 96;   // ws row stride (fp16 elements)
constexpr int PTS    = 8;    // points per wave (edge_kernel)
constexpr float LOG2E = 1.44269504f;

constexpr int FW1_SZ = 64 * 48;   // per-lane W1 frags: [lane][hb*3+kc][8]
constexpr int FW2_SZ = 64 * 40;   // per-lane W2 frags: [lane][nt][8]
constexpr int FB_SZ  = 64 * 16;   // per-lane biases (b1 x8, b2 x5, pad)
constexpr int FTAB_SZ = FW1_SZ + FW2_SZ + FB_SZ;   // 6656 f16

// point tables: Wm1t[64][104] + Wm2t[64][72] + Wsct[64][72] + bias[128]
constexpr int PW1_OFF = 0;
constexpr int PW2_OFF = 64 * X_LD;                 // 6656
constexpr int PSC_OFF = PW2_OFF + 64 * 72;         // 11264
constexpr int PB_OFF  = PSC_OFF + 64 * 72;         // 15872
constexpr int PTAB_SZ = PB_OFF + 128;              // 16000 f16

__device__ inline bool mask_is_int32(const void* m) {
    const uint32_t* p = (const uint32_t*)m;
    uint32_t acc = 0;
    #pragma unroll
    for (int i = 0; i < 16; ++i) acc |= p[i] & 0xFFFFFF00u;
    return acc == 0;
}

__device__ inline void lgkm_fence() {
    asm volatile("s_waitcnt lgkmcnt(0)" ::: "memory");
}

// cvt_pkrtz returns __fp16x2; bit_cast to our _Float16x2 (identical bits)
__device__ inline half2v pk2h(float a, float b) {
    return __builtin_bit_cast(half2v, __builtin_amdgcn_cvt_pkrtz(a, b));
}

// ====== kernel 0: points f32->fp16 (grid-stride) + table prep (blocks 0/1) ==
__global__ __launch_bounds__(256) void cvt_kernel(
    const float* __restrict__ in, _Float16* __restrict__ out, int n4,
    const float* __restrict__ w1, const float* __restrict__ b1,
    const float* __restrict__ w2, const float* __restrict__ b2,
    const float* __restrict__ wm1, const float* __restrict__ bm1,
    const float* __restrict__ wm2, const float* __restrict__ bm2,
    const float* __restrict__ wsc, const float* __restrict__ bsc,
    _Float16* __restrict__ ftab, _Float16* __restrict__ ptab)
{
    const int tid = threadIdx.x;
    if (blockIdx.x == 0) {
        // ---- edge fragment tables (per-lane MFMA layout) ----
        for (int i = tid; i < FW1_SZ; i += 256) {
            const int ln = i / 48, j = i % 48;
            const int hb = j / 24, kc = (j % 24) / 8, e = j % 8;
            const int mm = ln & 15, gg = ln >> 4;
            const int col = kc * 32 + gg * 8 + e;
            float v = 0.f;
            if (col < 64)      v = w1[(4 + col) * HID + hb * 16 + mm];
            else if (col < 68) v = w1[(col - 64) * HID + hb * 16 + mm];
            ftab[i] = (_Float16)v;
        }
        for (int i = tid; i < FW2_SZ; i += 256) {
            const int ln = i / 40, j = i % 40;
            const int nt = j / 8, e = j % 8;
            const int mm = ln & 15, gg = ln >> 4;
            const int sig = (e < 4) ? gg * 4 + e : 16 + gg * 4 + (e - 4);
            const int oc  = nt * 16 + mm;
            ftab[FW1_SZ + i] = (oc < CG) ? (_Float16)(w2[sig * CG + oc] * LOG2E)
                                         : (_Float16)0.f;
        }
        for (int i = tid; i < FB_SZ; i += 256) {
            const int ln = i / 16, j = i % 16;
            const int mm = ln & 15, gg = ln >> 4;
            float v = 0.f;
            if (j < 4)       v = b1[gg * 4 + j];
            else if (j < 8)  v = b1[16 + gg * 4 + (j - 4)];
            else if (j < 13) {
                const int nt = j - 8;
                v = (((nt * 16 + mm < CG) ? b2[nt * 16 + mm] : 0.f) - 2.0f) * LOG2E;
            }
            ftab[FW1_SZ + FW2_SZ + i] = (_Float16)v;
        }
    } else if (blockIdx.x == 1) {
        // ---- point-kernel weight tables ([c][k] col-major, padded) ----
        for (int i = tid; i < 64 * X_LD; i += 256) {
            const int c = i / X_LD, k = i % X_LD;
            ptab[PW1_OFF + i] = (k < CG) ? (_Float16)wm1[k * MH + c]
                                         : (_Float16)0.f;
        }
        for (int i = tid; i < 64 * 72; i += 256) {
            const int c = i / 72, k = i % 72;
            ptab[PW2_OFF + i] = (k < MH) ? (_Float16)wm2[k * MH + c]
                                         : (_Float16)0.f;
            ptab[PSC_OFF + i] = (k < MH) ? (_Float16)wsc[k * MH + c]
                                         : (_Float16)0.f;
        }
        for (int i = tid; i < 128; i += 256)
            ptab[PB_OFF + i] = (i < 64) ? (_Float16)bm1[i]
                                        : (_Float16)(bm2[i - 64] + bsc[i - 64]);
    }
    for (int i = blockIdx.x * 256 + tid; i < n4; i += gridDim.x * 256) {
        const float4 v = ((const float4*)in)[i];
        half4v h = { (_Float16)v.x, (_Float16)v.y, (_Float16)v.z, (_Float16)v.w };
        ((half4v*)out)[i] = h;
    }
}

// ================= kernel 1: edge MLP + masked softmax + aggregation ========
// 512 threads = 8 waves; each wave processes PTS points. All independent
// per-point metadata preloaded to LDS; only the pts16 gather + xyz_nn stay
// in-loop (2-deep double-buffered, issued a full body ahead).
__global__ __launch_bounds__(512, 6) void edge_kernel(
    const float* __restrict__ xyz, const float* __restrict__ xyz_nn,
    const _Float16* __restrict__ pts16, const int* __restrict__ knn,
    const float* __restrict__ dists, const void* __restrict__ mask,
    const _Float16* __restrict__ ftab,
    _Float16* __restrict__ aggw, int N)
{
    // per-wave X: 5 ref-first [16][16] f16 tiles (tile t = ref cols 16t..16t+15)
    __shared__ __align__(16) _Float16 sXt[8][5 * 256];
    __shared__ __align__(16) _Float16 sFrag[FW1_SZ + FW2_SZ];
    __shared__ __align__(16) _Float16 sFB[FB_SZ];
    // per-point metadata (block's 64 points), coalesced prologue loads
    __shared__ __align__(16) int      sPIdx[8][PTS][16];
    __shared__ __align__(16) _Float16 sPMk[8][PTS][16];
    __shared__ __align__(16) _Float16 sPD[8][PTS][16];
    __shared__ __align__(16) float    sPXyz[8][PTS][4];

    const int tid  = threadIdx.x;
    const int w    = tid >> 6;
    const int lane = tid & 63;
    const int m    = lane & 15;
    const int g    = lane >> 4;

    const bool is32 = mask_is_int32(mask);   // 64B scan, L1-hot, uniform

    // ---- fragment tables: vectorized contiguous copy from ws ----
    {
        const half8* __restrict__ ft8 = (const half8*)ftab;
        half8* __restrict__ fr8 = (half8*)sFrag;
        #pragma unroll 2
        for (int i = tid; i < (FW1_SZ + FW2_SZ) / 8; i += 512)
            fr8[i] = ft8[i];
        half8* __restrict__ fb8 = (half8*)sFB;
        for (int i = tid; i < FB_SZ / 8; i += 512)
            fb8[i] = ft8[(FW1_SZ + FW2_SZ) / 8 + i];
    }

    // ---- per-point metadata prologue (coalesced; clamped at N) ----
    const int pbase = blockIdx.x * (8 * PTS);
    for (int i = tid; i < 8 * PTS * 16; i += 512) {
        const int gi = min(pbase * 16 + i, N * 16 - 1);
        ((int*)sPIdx)[i] = knn[gi];
        const int mv = is32 ? ((const int*)mask)[gi]
                            : (int)((const uint8_t*)mask)[gi];
        ((_Float16*)sPMk)[i] = mv ? (_Float16)1.f : (_Float16)0.f;
        ((_Float16*)sPD)[i]  = (_Float16)dists[gi];
    }
    for (int i = tid; i < 8 * PTS * 4; i += 512) {
        const int pt = i >> 2, c = i & 3;
        const int gp_ = min(pbase + pt, N - 1);
        ((float*)sPXyz)[i] = (c < 3) ? xyz[gp_ * 3 + c] : 0.f;
    }

    // one-time: zero ref cols 68..79 (tile 4, cols 4..15)
    char* const XwB = (char*)&sXt[w][0];
    if (lane < 16) {
        half4v z = {};
        *(half4v*)(XwB + 4 * 512 + lane * 32 + 8)  = z;
        *(half4v*)(XwB + 4 * 512 + lane * 32 + 16) = z;
        *(half4v*)(XwB + 4 * 512 + lane * 32 + 24) = z;
    }
    __syncthreads();

    // ---- per-lane fragment loads (ds_read_b128; cheap to remat) ----
    half8 W1A[2][3];
    #pragma unroll
    for (int hb = 0; hb < 2; ++hb)
        #pragma unroll
        for (int kc = 0; kc < 3; ++kc)
            W1A[hb][kc] = *(const half8*)&sFrag[lane * 48 + (hb * 3 + kc) * 8];
    half8 W2B[5];
    #pragma unroll
    for (int nt = 0; nt < 5; ++nt)
        W2B[nt] = *(const half8*)&sFrag[FW1_SZ + lane * 40 + nt * 8];
    float b1v[4], b1w[4], b2v[5];
    {
        half4v bA = *(const half4v*)&sFB[lane * 16];
        half4v bB = *(const half4v*)&sFB[lane * 16 + 4];
        #pragma unroll
        for (int r = 0; r < 4; ++r) { b1v[r] = (float)bA[r]; b1w[r] = (float)bB[r]; }
        #pragma unroll
        for (int nt = 0; nt < 5; ++nt) b2v[nt] = (float)sFB[lane * 16 + 8 + nt];
    }
    const half4v ones = { (_Float16)1.f, (_Float16)1.f,
                          (_Float16)1.f, (_Float16)1.f };

    // ---- fixed per-lane X-tile write pointers + tr-read base ----
    auto tadr = [&](int c) -> char* {
        return XwB + ((c >> 4) * 512 + m * 32 + (c & 15) * 2);
    };
    half4v* const wF0lo = (half4v*)tadr(4 + 8 * g);    // feats g*8..g*8+3
    half4v* const wF0hi = (half4v*)tadr(8 + 8 * g);    // feats g*8+4..+7
    half4v* const wF1lo = (half4v*)tadr(36 + 8 * g);   // feats 32+g*8..+3
    half4v* const wF1hi = (half4v*)tadr(40 + 8 * g);   // feats 32+g*8+4..+7
    half4v* const wGeo  = (half4v*)tadr(0);            // g==0: ref cols 0..3
    const uint32_t xrd = (uint32_t)(uintptr_t)XwB + lane * 8;

    const int nbase = (blockIdx.x * 8 + w) * PTS;

    // -------- 2-deep gather staging (compile-time buf idx) --------
    float stNx[2], stNy[2], stNz[2];
    half8 stF0[2], stF1[2];

    auto issueB = [&](int pp, auto bfc) {   // idx from LDS -> no vmcnt wait
        constexpr int bf = decltype(bfc)::value;
        const int idx = sPIdx[w][pp][m];
        stF0[bf] = *(const half8*)&pts16[(size_t)idx * CIN + g * 8];
        stF1[bf] = *(const half8*)&pts16[(size_t)idx * CIN + 32 + g * 8];
        if (g == 0) {
            stNx[bf] = xyz_nn[idx * 3 + 0];
            stNy[bf] = xyz_nn[idx * 3 + 1];
            stNz[bf] = xyz_nn[idx * 3 + 2];
        }
    };

    auto body = [&](int p, auto curc, auto nxtc) {
        constexpr int buf = decltype(curc)::value;
        const bool val = (nbase + p < N);
        const int n = val ? nbase + p : 0;

        // ---- per-point metadata from LDS (broadcast / tiny reads) ----
        half4v mk4 = *(const half4v*)&sPMk[w][p][g * 4];
        const half2v mk01 = { mk4[0], mk4[1] };
        const half2v mk23 = { mk4[2], mk4[3] };
        half8 geoF = {};
        if (g == 0) {
            const float cx = sPXyz[w][p][0];
            const float cy = sPXyz[w][p][1];
            const float cz = sPXyz[w][p][2];
            geoF[0] = (_Float16)(stNx[buf] - cx);
            geoF[1] = (_Float16)(stNy[buf] - cy);
            geoF[2] = (_Float16)(stNz[buf] - cz);
            geoF[3] = sPD[w][p][m];
        }

        // ---- X tile writes (aligned b64s, fixed addrs) ----
        half4v f0lo, f0hi, f1lo, f1hi;
        #pragma unroll
        for (int j = 0; j < 4; ++j) {
            f0lo[j] = stF0[buf][j]; f0hi[j] = stF0[buf][4 + j];
            f1lo[j] = stF1[buf][j]; f1hi[j] = stF1[buf][4 + j];
        }
        *wF0lo = f0lo; *wF0hi = f0hi; *wF1lo = f1lo; *wF1hi = f1hi;
        if (g == 0) {
            half4v gv = { geoF[0], geoF[1], geoF[2], geoF[3] };
            *wGeo = gv;
        }
        lgkm_fence();    // X writes complete before transpose reads

        // ---- issue all 5 transpose reads (lane(m,g) elem j = X[g*4+j][16nt+m])
        half4v xq0, xq1, xq2, xq3, xq4;
        asm volatile(
            "ds_read_b64_tr_b16 %0, %5\n\t"
            "ds_read_b64_tr_b16 %1, %5 offset:512\n\t"
            "ds_read_b64_tr_b16 %2, %5 offset:1024\n\t"
            "ds_read_b64_tr_b16 %3, %5 offset:1536\n\t"
            "ds_read_b64_tr_b16 %4, %5 offset:2048"
            : "=&v"(xq0), "=&v"(xq1), "=&v"(xq2), "=&v"(xq3), "=&v"(xq4)
            : "v"(xrd));

        // gather for p+1: idx is an LDS read -> issues immediately, covered
        // by layer1 + layer2 + softmax (~450 cyc)
        issueB(p + 1 < PTS ? p + 1 : PTS - 1, nxtc);

        // ---- layer 1 (transposed): h^T = W1^T @ X^T, 6 MFMA, no LDS ----
        f32x4 a0 = {0.f, 0.f, 0.f, 0.f};
        f32x4 a1 = {0.f, 0.f, 0.f, 0.f};
        a0 = __builtin_amdgcn_mfma_f32_16x16x32_f16(W1A[0][0], stF0[buf], a0, 0, 0, 0);
        a1 = __builtin_amdgcn_mfma_f32_16x16x32_f16(W1A[1][0], stF0[buf], a1, 0, 0, 0);
        a0 = __builtin_amdgcn_mfma_f32_16x16x32_f16(W1A[0][1], stF1[buf], a0, 0, 0, 0);
        a1 = __builtin_amdgcn_mfma_f32_16x16x32_f16(W1A[1][1], stF1[buf], a1, 0, 0, 0);
        a0 = __builtin_amdgcn_mfma_f32_16x16x32_f16(W1A[0][2], geoF,      a0, 0, 0, 0);
        a1 = __builtin_amdgcn_mfma_f32_16x16x32_f16(W1A[1][2], geoF,      a1, 0, 0, 0);

        // D-frag -> layer-2 A-frag (sigma permutation), bias+relu+cvt only
        half8 A2;
        #pragma unroll
        for (int r = 0; r < 4; ++r) {
            A2[r]     = (_Float16)fmaxf(a0[r] + b1v[r], 0.f);
            A2[4 + r] = (_Float16)fmaxf(a1[r] + b1w[r], 0.f);
        }

        asm volatile("s_waitcnt lgkmcnt(0)" ::: "memory");
        __builtin_amdgcn_sched_barrier(0);       // rule #18: pin tr-read data

        const half4v xqs[5] = { xq0, xq1, xq2, xq3, xq4 };
        const size_t obase = (size_t)n * AGG_LD;

        #pragma unroll
        for (int nt = 0; nt < 5; ++nt) {
            f32x4 acc = {0.f, 0.f, 0.f, 0.f};
            acc = __builtin_amdgcn_mfma_f32_16x16x32_f16(A2, W2B[nt], acc, 0, 0, 0);
            const float bb = b2v[nt];        // (b2-2)*log2e, shift cancels
            // e = exp2(acc+bb) * mask, packed fp16
            half2v ef01 = pk2h(__builtin_amdgcn_exp2f(acc[0] + bb),
                               __builtin_amdgcn_exp2f(acc[1] + bb)) * mk01;
            half2v ef23 = pk2h(__builtin_amdgcn_exp2f(acc[2] + bb),
                               __builtin_amdgcn_exp2f(acc[3] + bb)) * mk23;
            const half2v xlo = { xqs[nt][0], xqs[nt][1] };
            const half2v xhi = { xqs[nt][2], xqs[nt][3] };
            const half2v exf01 = ef01 * xlo;
            const half2v exf23 = ef23 * xhi;
            const half4v ef  = { ef01[0], ef01[1], ef23[0], ef23[1] };
            const half4v exf = { exf01[0], exf01[1], exf23[0], exf23[1] };
            // D-frag == K=16 B-frag: ones-row MFMA -> column sums, no shfl
            f32x4 sden = {0.f, 0.f, 0.f, 0.f};
            f32x4 snum = {0.f, 0.f, 0.f, 0.f};
            sden = __builtin_amdgcn_mfma_f32_16x16x16f16(ones, ef,  sden, 0, 0, 0);
            snum = __builtin_amdgcn_mfma_f32_16x16x16f16(ones, exf, snum, 0, 0, 0);
            const float aggv = snum[0] * __builtin_amdgcn_rcpf(sden[0] + 1e-8f);
            if (val && g == (nt & 3)) aggw[obase + nt * 16 + m] = (_Float16)aggv;
        }
        if (val && lane < 16) aggw[obase + 80 + lane] = (_Float16)0.f;
        // no trailing fence: tr-reads completed at the waitcnt above
    };

    issueB(0, IC<0>{});
    #pragma unroll
    for (int p = 0; p < PTS; p += 2) {
        body(p,     IC<0>{}, IC<1>{});
        body(p + 1, IC<1>{}, IC<0>{});
    }
}

// ================= kernel 2: point MLP + shortcut + xyz passthrough =========
// 512 threads = 8 waves; each wave owns one 16-point tile.
__global__ __launch_bounds__(512) void point_kernel(
    const float* __restrict__ xyz, const _Float16* __restrict__ pts16,
    const _Float16* __restrict__ aggw, const _Float16* __restrict__ ptab,
    float* __restrict__ out, int N, int ntiles)
{
    __shared__ __align__(16) _Float16 sW[PTAB_SZ];   // Wm1t|Wm2t|Wsct|bias
    __shared__ __align__(16) _Float16 sH2[8][16 * 72];

    const int tid = threadIdx.x;

    // fold xyz passthrough copy
    for (int gid = blockIdx.x * 512 + tid; gid < 3 * N; gid += gridDim.x * 512)
        out[gid] = xyz[gid];

    // weight tables: vectorized contiguous copy (2000 x half8)
    {
        const half8* __restrict__ pt8 = (const half8*)ptab;
        half8* __restrict__ sw8 = (half8*)sW;
        #pragma unroll 4
        for (int i = tid; i < PTAB_SZ / 8; i += 512)
            sw8[i] = pt8[i];
    }
    __syncthreads();

    const _Float16* __restrict__ sWm1 = &sW[PW1_OFF];
    const _Float16* __restrict__ sWm2 = &sW[PW2_OFF];
    const _Float16* __restrict__ sWsc = &sW[PSC_OFF];

    const int w = tid >> 6, lane = tid & 63;
    const int m = lane & 15, g = lane >> 4;
    const int t = blockIdx.x * 8 + w;
    if (t >= ntiles) return;          // no barriers after this point
    const int row0 = t * 16;
    _Float16* __restrict__ H2 = sH2[w];

    const int rl = min(row0 + m, N - 1);   // clamped load row

    // ---- m1: h2 = relu(agg[16,96] @ Wm1[96,64]) : 12 MFMA ----
    f32x4 acc[4] = {{0.f,0.f,0.f,0.f},{0.f,0.f,0.f,0.f},
                    {0.f,0.f,0.f,0.f},{0.f,0.f,0.f,0.f}};
    #pragma unroll
    for (int kc = 0; kc < 3; ++kc) {
        const int ko = kc * 32 + g * 8;
        half8 a = *(const half8*)&aggw[(size_t)rl * AGG_LD + ko];
        #pragma unroll
        for (int nt = 0; nt < 4; ++nt) {
            half8 b = *(const half8*)&sWm1[(nt * 16 + m) * X_LD + ko];
            acc[nt] = __builtin_amdgcn_mfma_f32_16x16x32_f16(a, b, acc[nt], 0, 0, 0);
        }
    }
    #pragma unroll
    for (int nt = 0; nt < 4; ++nt) {
        const float bb = (float)sW[PB_OFF + nt * 16 + m];
        #pragma unroll
        for (int r = 0; r < 4; ++r)
            H2[(g * 4 + r) * 72 + nt * 16 + m] = (_Float16)fmaxf(acc[nt][r] + bb, 0.f);
    }
    lgkm_fence();

    // ---- m2 + shortcut: out = h2@Wm2 + pts@Wsc + (bm2+bsc) : 16 MFMA ----
    f32x4 acc2[4] = {{0.f,0.f,0.f,0.f},{0.f,0.f,0.f,0.f},
                     {0.f,0.f,0.f,0.f},{0.f,0.f,0.f,0.f}};
    #pragma unroll
    for (int kc = 0; kc < 2; ++kc) {
        const int ko = kc * 32 + g * 8;
        half8 ah = *(const half8*)&H2[m * 72 + ko];
        half8 ap = *(const half8*)&pts16[(size_t)rl * CIN + ko];
        #pragma unroll
        for (int nt = 0; nt < 4; ++nt) {
            half8 b2f = *(const half8*)&sWm2[(nt * 16 + m) * 72 + ko];
            half8 bsf = *(const half8*)&sWsc[(nt * 16 + m) * 72 + ko];
            acc2[nt] = __builtin_amdgcn_mfma_f32_16x16x32_f16(ah, b2f, acc2[nt], 0, 0, 0);
            acc2[nt] = __builtin_amdgcn_mfma_f32_16x16x32_f16(ap, bsf, acc2[nt], 0, 0, 0);
        }
    }
    float* __restrict__ outp = out + (size_t)3 * N;
    #pragma unroll
    for (int nt = 0; nt < 4; ++nt) {
        const float bb = (float)sW[PB_OFF + 64 + nt * 16 + m];
        #pragma unroll
        for (int r = 0; r < 4; ++r) {
            const int row = row0 + g * 4 + r;
            if (row < N) outp[(size_t)row * MH + nt * 16 + m] = acc2[nt][r] + bb;
        }
    }
}

// ================= fallback: verified R2 fused fp32 kernel ==================
__global__ __launch_bounds__(256) void fused_ip_kernel(
    const float* __restrict__ xyz, const float* __restrict__ xyz_nn,
    const float* __restrict__ points, const int* __restrict__ knn,
    const float* __restrict__ dists, const void* __restrict__ mask,
    const float* __restrict__ w1, const float* __restrict__ b1,
    const float* __restrict__ w2, const float* __restrict__ b2,
    const float* __restrict__ wm1, const float* __restrict__ bm1,
    const float* __restrict__ wm2, const float* __restrict__ bm2,
    const float* __restrict__ wsc, const float* __restrict__ bsc,
    float* __restrict__ out, int N)
{
    __shared__ __align__(16) float gp[4][K][72];
    __shared__ float hb [4][K][33];
    __shared__ float dkb[4][K][69];
    __shared__ float mkb[4][K];
    __shared__ int   sidx[4][K];
    __shared__ float aggb[4][CG];
    __shared__ float h2b[4][MH];
    __shared__ float ptb[4][CIN];

    const int tid  = threadIdx.x;
    const int w    = tid >> 6;
    const int lane = tid & 63;
    {
        int gid = blockIdx.x * 256 + tid;
        if (gid < 3 * N) out[gid] = xyz[gid];
    }
    int n = blockIdx.x * 4 + w;
    const bool valid = (n < N);
    if (!valid) n = 0;
    float* __restrict__ outp = out + (size_t)3 * N;

    if (lane < K) {
        const int idx = knn[n * K + lane];
        sidx[w][lane] = idx;
        const bool mv = mask_is_int32(mask)
            ? (((const int*)mask)[n * K + lane] != 0)
            : (((const uint8_t*)mask)[n * K + lane] != 0);
        mkb[w][lane]  = mv ? 1.0f : 0.0f;
        const float cx = xyz[n * 3 + 0], cy = xyz[n * 3 + 1], cz = xyz[n * 3 + 2];
        gp[w][lane][0] = xyz_nn[idx * 3 + 0] - cx;
        gp[w][lane][1] = xyz_nn[idx * 3 + 1] - cy;
        gp[w][lane][2] = xyz_nn[idx * 3 + 2] - cz;
        gp[w][lane][3] = dists[n * K + lane];
    }
    ptb[w][lane] = points[(size_t)n * CIN + lane];
    __syncthreads();
    for (int k = 0; k < K; ++k) {
        const int idx = sidx[w][k];
        gp[w][k][4 + lane] = points[(size_t)idx * CIN + lane];
    }
    __syncthreads();
    {
        const int j  = lane & 31;
        const int kh = lane >> 5;
        float acc[8];
        const float bj = b1[j];
        #pragma unroll
        for (int kk = 0; kk < 8; ++kk) acc[kk] = bj;
        for (int c4 = 0; c4 < 17; ++c4) {
            float w1v[4];
            #pragma unroll
            for (int i = 0; i < 4; ++i) w1v[i] = w1[(c4 * 4 + i) * HID + j];
            #pragma unroll
            for (int kk = 0; kk < 8; ++kk) {
                const int k = kk * 2 + kh;
                const float4 g4 = *reinterpret_cast<const float4*>(&gp[w][k][c4 * 4]);
                acc[kk] += g4.x * w1v[0] + g4.y * w1v[1] + g4.z * w1v[2] + g4.w * w1v[3];
            }
        }
        #pragma unroll
        for (int kk = 0; kk < 8; ++kk) {
            const int k = kk * 2 + kh;
            hb[w][k][j] = fmaxf(acc[kk], 0.0f);
        }
    }
    __syncthreads();
    {
        const int k = lane >> 2;
        const int q = lane & 3;
        float acc[17];
        #pragma unroll
        for (int i = 0; i < 17; ++i) acc[i] = b2[q * 17 + i];
        for (int j2 = 0; j2 < HID; ++j2) {
            const float hv = hb[w][k][j2];
            const float* __restrict__ w2r = &w2[j2 * CG + q * 17];
            #pragma unroll
            for (int i = 0; i < 17; ++i) acc[i] += hv * w2r[i];
        }
        #pragma unroll
        for (int i = 0; i < 17; ++i) dkb[w][k][q * 17 + i] = acc[i];
    }
    __syncthreads();
    {
        #pragma unroll
        for (int rep = 0; rep < 2; ++rep) {
            const int c = rep * 64 + lane;
            if (c < CG) {
                float v[K];
                float mm = -1e30f;
                #pragma unroll
                for (int k = 0; k < K; ++k) { v[k] = dkb[w][k][c]; mm = fmaxf(mm, v[k]); }
                float s = 0.0f;
                #pragma unroll
                for (int k = 0; k < K; ++k) {
                    const float e = __expf(v[k] - mm) * mkb[w][k];
                    v[k] = e; s += e;
                }
                const float inv = 1.0f / (s + 1e-8f);
                float a = 0.0f;
                #pragma unroll
                for (int k = 0; k < K; ++k) a += v[k] * gp[w][k][c];
                aggb[w][c] = a * inv;
            }
        }
    }
    __syncthreads();
    {
        float acc = bm1[lane];
        for (int c = 0; c < CG; ++c) acc += aggb[w][c] * wm1[c * MH + lane];
        h2b[w][lane] = fmaxf(acc, 0.0f);
    }
    __syncthreads();
    {
        float acc = bm2[lane] + bsc[lane];
        for (int j2 = 0; j2 < MH; ++j2) acc += h2b[w][j2] * wm2[j2 * MH + lane];
        for (int c = 0; c < CIN; ++c)  acc += ptb[w][c] * wsc[c * MH + lane];
        if (valid) outp[(size_t)n * MH + lane] = acc;
    }
}

} // namespace

extern "C" void kernel_launch(void* const* d_in, const int* in_sizes, int n_in,
                              void* d_out, int out_size, void* d_ws, size_t ws_size,
                              hipStream_t stream)
{
    const float*   xyz    = (const float*)d_in[0];
    const float*   xyz_nn = (const float*)d_in[1];
    const float*   points = (const float*)d_in[2];
    const int*     knn    = (const int*)d_in[3];
    const float*   dists  = (const float*)d_in[4];
    const void*    mask   = d_in[5];
    const float*   w1  = (const float*)d_in[6];
    const float*   b1  = (const float*)d_in[7];
    const float*   w2  = (const float*)d_in[8];
    const float*   b2  = (const float*)d_in[9];
    const float*   wm1 = (const float*)d_in[10];
    const float*   bm1 = (const float*)d_in[11];
    const float*   wm2 = (const float*)d_in[12];
    const float*   bm2 = (const float*)d_in[13];
    const float*   wsc = (const float*)d_in[14];
    const float*   bsc = (const float*)d_in[15];

    float* out = (float*)d_out;
    const int N = in_sizes[0] / 3;
    const size_t agg_bytes  = (size_t)N * AGG_LD * sizeof(_Float16);
    const size_t pts_bytes  = (size_t)N * CIN * sizeof(_Float16);
    const size_t ftab_bytes = (size_t)FTAB_SZ * sizeof(_Float16);
    const size_t ptab_bytes = (size_t)PTAB_SZ * sizeof(_Float16);

    if (ws_size >= agg_bytes + pts_bytes + ftab_bytes + ptab_bytes) {
        _Float16* aggw  = (_Float16*)d_ws;
        _Float16* pts16 = (_Float16*)((char*)d_ws + agg_bytes);
        _Float16* ftab  = (_Float16*)((char*)d_ws + agg_bytes + pts_bytes);
        _Float16* ptab  = (_Float16*)((char*)d_ws + agg_bytes + pts_bytes + ftab_bytes);

        hipLaunchKernelGGL(cvt_kernel, dim3(2048), dim3(256), 0, stream,
                           points, pts16, N * CIN / 4,
                           w1, b1, w2, b2, wm1, bm1, wm2, bm2, wsc, bsc,
                           ftab, ptab);

        const int ppb     = 8 * PTS;                 // points per block
        const int blocks1 = (N + ppb - 1) / ppb;
        hipLaunchKernelGGL(edge_kernel, dim3(blocks1), dim3(512), 0, stream,
                           xyz, xyz_nn, pts16, knn, dists, mask,
                           ftab, aggw, N);

        const int ntiles  = (N + 15) / 16;
        const int blocks2 = (ntiles + 7) / 8;
        hipLaunchKernelGGL(point_kernel, dim3(blocks2), dim3(512), 0, stream,
                           xyz, pts16, aggw, ptab, out, N, ntiles);
    } else {
        const int blocks = (N + 3) / 4;
        hipLaunchKernelGGL(fused_ip_kernel, dim3(blocks), dim3(256), 0, stream,
                           xyz, xyz_nn, points, knn, dists, mask,
                           w1, b1, w2, b2, wm1, bm1, wm2, bm2, wsc, bsc,
                           out, N);
    }
}

// Round 18
// 96.683 us; speedup vs baseline: 2.7477x; 2.7477x over previous
//
#include <hip/hip_runtime.h>
#include <cstdint>

// inter_prediction: fused point-cloud edge-conv on MI355X (gfx950).
// Inputs (setup_inputs order):
//  0 xyz [1,N,3] f32 | 1 xyz_nn [1,N,3] f32 | 2 points [1,N,64] f32
//  3 knn [1,N,16] i32 | 4 dists [1,N,16] f32 | 5 mask [1,N,16] bool (layout
//  runtime-detected int32-vs-byte) | 6..15 weights/biases f32.
// Output: concat(xyz.flat [3N], out.flat [64N]) f32
//
// MFMA mappings (verified learn_hip m89/m91): 16x16x32_f16 A: row=lane&15,
// k=(lane>>4)*8+e. B: col=lane&15, k=(lane>>4)*8+e. C/D: col=lane&15,
// row=(lane>>4)*4+reg. 16x16x16f16: k=(lane>>4)*4+j -> a D-fragment IS a
// valid K=16 B-fragment (ones-row MFMA gives per-column sums, no shuffles).
//
// R18: empirical law from R14/R15/R17: VGPR budget ~ 256/min_waves_arg
// ((512,4)->64 OK, (512,6)->40 spill, (512,8)->32 disaster). Edge MUST
// stay at (512,4). This round = R16 (112.5us best) + R17's sound part
// only: point-kernel weight tables precomputed in cvt_kernel block 1
// (prologue becomes a contiguous half8 copy), prep folded into cvt.

namespace {

typedef _Float16 half8  __attribute__((ext_vector_type(8)));
typedef _Float16 half4v __attribute__((ext_vector_type(4)));
typedef _Float16 half2v __attribute__((ext_vector_type(2)));
typedef float    f32x4  __attribute__((ext_vector_type(4)));

template <int I> struct IC { static constexpr int value = I; };

constexpr int K   = 16;
constexpr int CIN = 64;
constexpr int CG  = 68;   // 4 + CIN
constexpr int HID = 32;
constexpr int MH  = 64;

constexpr int X_LD   = 104;  // point_kernel Wm1 stride
constexpr int AGG_LD = 96;   // ws row stride (fp16 elements)
constexpr int PTS    = 8;    // points per wave (edge_kernel)
constexpr float LOG2E = 1.44269504f;

constexpr int FW1_SZ = 64 * 48;   // per-lane W1 frags: [lane][hb*3+kc][8]
constexpr int FW2_SZ = 64 * 40;   // per-lane W2 frags: [lane][nt][8]
constexpr int FB_SZ  = 64 * 16;   // per-lane biases (b1 x8, b2 x5, pad)
constexpr int FTAB_SZ = FW1_SZ + FW2_SZ + FB_SZ;   // 6656 f16

// point tables: Wm1t[64][104] + Wm2t[64][72] + Wsct[64][72] + bias[128]
constexpr int PW1_OFF = 0;
constexpr int PW2_OFF = 64 * X_LD;                 // 6656
constexpr int PSC_OFF = PW2_OFF + 64 * 72;         // 11264
constexpr int PB_OFF  = PSC_OFF + 64 * 72;         // 15872
constexpr int PTAB_SZ = PB_OFF + 128;              // 16000 f16

__device__ inline bool mask_is_int32(const void* m) {
    const uint32_t* p = (const uint32_t*)m;
    uint32_t acc = 0;
    #pragma unroll
    for (int i = 0; i < 16; ++i) acc |= p[i] & 0xFFFFFF00u;
    return acc == 0;
}

__device__ inline void lgkm_fence() {
    asm volatile("s_waitcnt lgkmcnt(0)" ::: "memory");
}

// cvt_pkrtz returns __fp16x2; bit_cast to our _Float16x2 (identical bits)
__device__ inline half2v pk2h(float a, float b) {
    return __builtin_bit_cast(half2v, __builtin_amdgcn_cvt_pkrtz(a, b));
}

// ====== kernel 0: points f32->fp16 (grid-stride) + table prep (blocks 0/1) ==
__global__ __launch_bounds__(256) void cvt_kernel(
    const float* __restrict__ in, _Float16* __restrict__ out, int n4,
    const float* __restrict__ w1, const float* __restrict__ b1,
    const float* __restrict__ w2, const float* __restrict__ b2,
    const float* __restrict__ wm1, const float* __restrict__ bm1,
    const float* __restrict__ wm2, const float* __restrict__ bm2,
    const float* __restrict__ wsc, const float* __restrict__ bsc,
    _Float16* __restrict__ ftab, _Float16* __restrict__ ptab)
{
    const int tid = threadIdx.x;
    if (blockIdx.x == 0) {
        // ---- edge fragment tables (per-lane MFMA layout) ----
        for (int i = tid; i < FW1_SZ; i += 256) {
            const int ln = i / 48, j = i % 48;
            const int hb = j / 24, kc = (j % 24) / 8, e = j % 8;
            const int mm = ln & 15, gg = ln >> 4;
            const int col = kc * 32 + gg * 8 + e;
            float v = 0.f;
            if (col < 64)      v = w1[(4 + col) * HID + hb * 16 + mm];
            else if (col < 68) v = w1[(col - 64) * HID + hb * 16 + mm];
            ftab[i] = (_Float16)v;
        }
        for (int i = tid; i < FW2_SZ; i += 256) {
            const int ln = i / 40, j = i % 40;
            const int nt = j / 8, e = j % 8;
            const int mm = ln & 15, gg = ln >> 4;
            const int sig = (e < 4) ? gg * 4 + e : 16 + gg * 4 + (e - 4);
            const int oc  = nt * 16 + mm;
            ftab[FW1_SZ + i] = (oc < CG) ? (_Float16)(w2[sig * CG + oc] * LOG2E)
                                         : (_Float16)0.f;
        }
        for (int i = tid; i < FB_SZ; i += 256) {
            const int ln = i / 16, j = i % 16;
            const int mm = ln & 15, gg = ln >> 4;
            float v = 0.f;
            if (j < 4)       v = b1[gg * 4 + j];
            else if (j < 8)  v = b1[16 + gg * 4 + (j - 4)];
            else if (j < 13) {
                const int nt = j - 8;
                v = (((nt * 16 + mm < CG) ? b2[nt * 16 + mm] : 0.f) - 2.0f) * LOG2E;
            }
            ftab[FW1_SZ + FW2_SZ + i] = (_Float16)v;
        }
    } else if (blockIdx.x == 1) {
        // ---- point-kernel weight tables ([c][k] col-major, padded) ----
        for (int i = tid; i < 64 * X_LD; i += 256) {
            const int c = i / X_LD, k = i % X_LD;
            ptab[PW1_OFF + i] = (k < CG) ? (_Float16)wm1[k * MH + c]
                                         : (_Float16)0.f;
        }
        for (int i = tid; i < 64 * 72; i += 256) {
            const int c = i / 72, k = i % 72;
            ptab[PW2_OFF + i] = (k < MH) ? (_Float16)wm2[k * MH + c]
                                         : (_Float16)0.f;
            ptab[PSC_OFF + i] = (k < MH) ? (_Float16)wsc[k * MH + c]
                                         : (_Float16)0.f;
        }
        for (int i = tid; i < 128; i += 256)
            ptab[PB_OFF + i] = (i < 64) ? (_Float16)bm1[i]
                                        : (_Float16)(bm2[i - 64] + bsc[i - 64]);
    }
    for (int i = blockIdx.x * 256 + tid; i < n4; i += gridDim.x * 256) {
        const float4 v = ((const float4*)in)[i];
        half4v h = { (_Float16)v.x, (_Float16)v.y, (_Float16)v.z, (_Float16)v.w };
        ((half4v*)out)[i] = h;
    }
}

// ================= kernel 1: edge MLP + masked softmax + aggregation ========
// 512 threads = 8 waves; each wave processes PTS points. All independent
// per-point metadata preloaded to LDS; only the pts16 gather + xyz_nn stay
// in-loop (2-deep double-buffered, issued a full body ahead).
__global__ __launch_bounds__(512, 4) void edge_kernel(
    const float* __restrict__ xyz, const float* __restrict__ xyz_nn,
    const _Float16* __restrict__ pts16, const int* __restrict__ knn,
    const float* __restrict__ dists, const void* __restrict__ mask,
    const _Float16* __restrict__ ftab,
    _Float16* __restrict__ aggw, int N)
{
    // per-wave X: 5 ref-first [16][16] f16 tiles (tile t = ref cols 16t..16t+15)
    __shared__ __align__(16) _Float16 sXt[8][5 * 256];
    __shared__ __align__(16) _Float16 sFrag[FW1_SZ + FW2_SZ];
    __shared__ __align__(16) _Float16 sFB[FB_SZ];
    // per-point metadata (block's 64 points), coalesced prologue loads
    __shared__ __align__(16) int      sPIdx[8][PTS][16];
    __shared__ __align__(16) _Float16 sPMk[8][PTS][16];
    __shared__ __align__(16) _Float16 sPD[8][PTS][16];
    __shared__ __align__(16) float    sPXyz[8][PTS][4];

    const int tid  = threadIdx.x;
    const int w    = tid >> 6;
    const int lane = tid & 63;
    const int m    = lane & 15;
    const int g    = lane >> 4;

    const bool is32 = mask_is_int32(mask);   // 64B scan, L1-hot, uniform

    // ---- fragment tables: vectorized contiguous copy from ws ----
    {
        const half8* __restrict__ ft8 = (const half8*)ftab;
        half8* __restrict__ fr8 = (half8*)sFrag;
        #pragma unroll 2
        for (int i = tid; i < (FW1_SZ + FW2_SZ) / 8; i += 512)
            fr8[i] = ft8[i];
        half8* __restrict__ fb8 = (half8*)sFB;
        for (int i = tid; i < FB_SZ / 8; i += 512)
            fb8[i] = ft8[(FW1_SZ + FW2_SZ) / 8 + i];
    }

    // ---- per-point metadata prologue (coalesced; clamped at N) ----
    const int pbase = blockIdx.x * (8 * PTS);
    for (int i = tid; i < 8 * PTS * 16; i += 512) {
        const int gi = min(pbase * 16 + i, N * 16 - 1);
        ((int*)sPIdx)[i] = knn[gi];
        const int mv = is32 ? ((const int*)mask)[gi]
                            : (int)((const uint8_t*)mask)[gi];
        ((_Float16*)sPMk)[i] = mv ? (_Float16)1.f : (_Float16)0.f;
        ((_Float16*)sPD)[i]  = (_Float16)dists[gi];
    }
    for (int i = tid; i < 8 * PTS * 4; i += 512) {
        const int pt = i >> 2, c = i & 3;
        const int gp_ = min(pbase + pt, N - 1);
        ((float*)sPXyz)[i] = (c < 3) ? xyz[gp_ * 3 + c] : 0.f;
    }

    // one-time: zero ref cols 68..79 (tile 4, cols 4..15)
    char* const XwB = (char*)&sXt[w][0];
    if (lane < 16) {
        half4v z = {};
        *(half4v*)(XwB + 4 * 512 + lane * 32 + 8)  = z;
        *(half4v*)(XwB + 4 * 512 + lane * 32 + 16) = z;
        *(half4v*)(XwB + 4 * 512 + lane * 32 + 24) = z;
    }
    __syncthreads();

    // ---- per-lane fragment loads (ds_read_b128; cheap to remat) ----
    half8 W1A[2][3];
    #pragma unroll
    for (int hb = 0; hb < 2; ++hb)
        #pragma unroll
        for (int kc = 0; kc < 3; ++kc)
            W1A[hb][kc] = *(const half8*)&sFrag[lane * 48 + (hb * 3 + kc) * 8];
    half8 W2B[5];
    #pragma unroll
    for (int nt = 0; nt < 5; ++nt)
        W2B[nt] = *(const half8*)&sFrag[FW1_SZ + lane * 40 + nt * 8];
    float b1v[4], b1w[4], b2v[5];
    {
        half4v bA = *(const half4v*)&sFB[lane * 16];
        half4v bB = *(const half4v*)&sFB[lane * 16 + 4];
        #pragma unroll
        for (int r = 0; r < 4; ++r) { b1v[r] = (float)bA[r]; b1w[r] = (float)bB[r]; }
        #pragma unroll
        for (int nt = 0; nt < 5; ++nt) b2v[nt] = (float)sFB[lane * 16 + 8 + nt];
    }
    const half4v ones = { (_Float16)1.f, (_Float16)1.f,
                          (_Float16)1.f, (_Float16)1.f };

    // ---- fixed per-lane X-tile write pointers + tr-read base ----
    auto tadr = [&](int c) -> char* {
        return XwB + ((c >> 4) * 512 + m * 32 + (c & 15) * 2);
    };
    half4v* const wF0lo = (half4v*)tadr(4 + 8 * g);    // feats g*8..g*8+3
    half4v* const wF0hi = (half4v*)tadr(8 + 8 * g);    // feats g*8+4..+7
    half4v* const wF1lo = (half4v*)tadr(36 + 8 * g);   // feats 32+g*8..+3
    half4v* const wF1hi = (half4v*)tadr(40 + 8 * g);   // feats 32+g*8+4..+7
    half4v* const wGeo  = (half4v*)tadr(0);            // g==0: ref cols 0..3
    const uint32_t xrd = (uint32_t)(uintptr_t)XwB + lane * 8;

    const int nbase = (blockIdx.x * 8 + w) * PTS;

    // -------- 2-deep gather staging (compile-time buf idx) --------
    float stNx[2], stNy[2], stNz[2];
    half8 stF0[2], stF1[2];

    auto issueB = [&](int pp, auto bfc) {   // idx from LDS -> no vmcnt wait
        constexpr int bf = decltype(bfc)::value;
        const int idx = sPIdx[w][pp][m];
        stF0[bf] = *(const half8*)&pts16[(size_t)idx * CIN + g * 8];
        stF1[bf] = *(const half8*)&pts16[(size_t)idx * CIN + 32 + g * 8];
        if (g == 0) {
            stNx[bf] = xyz_nn[idx * 3 + 0];
            stNy[bf] = xyz_nn[idx * 3 + 1];
            stNz[bf] = xyz_nn[idx * 3 + 2];
        }
    };

    auto body = [&](int p, auto curc, auto nxtc) {
        constexpr int buf = decltype(curc)::value;
        const bool val = (nbase + p < N);
        const int n = val ? nbase + p : 0;

        // ---- per-point metadata from LDS (broadcast / tiny reads) ----
        half4v mk4 = *(const half4v*)&sPMk[w][p][g * 4];
        const half2v mk01 = { mk4[0], mk4[1] };
        const half2v mk23 = { mk4[2], mk4[3] };
        half8 geoF = {};
        if (g == 0) {
            const float cx = sPXyz[w][p][0];
            const float cy = sPXyz[w][p][1];
            const float cz = sPXyz[w][p][2];
            geoF[0] = (_Float16)(stNx[buf] - cx);
            geoF[1] = (_Float16)(stNy[buf] - cy);
            geoF[2] = (_Float16)(stNz[buf] - cz);
            geoF[3] = sPD[w][p][m];
        }

        // ---- X tile writes (aligned b64s, fixed addrs) ----
        half4v f0lo, f0hi, f1lo, f1hi;
        #pragma unroll
        for (int j = 0; j < 4; ++j) {
            f0lo[j] = stF0[buf][j]; f0hi[j] = stF0[buf][4 + j];
            f1lo[j] = stF1[buf][j]; f1hi[j] = stF1[buf][4 + j];
        }
        *wF0lo = f0lo; *wF0hi = f0hi; *wF1lo = f1lo; *wF1hi = f1hi;
        if (g == 0) {
            half4v gv = { geoF[0], geoF[1], geoF[2], geoF[3] };
            *wGeo = gv;
        }
        lgkm_fence();    // X writes complete before transpose reads

        // ---- issue all 5 transpose reads (lane(m,g) elem j = X[g*4+j][16nt+m])
        half4v xq0, xq1, xq2, xq3, xq4;
        asm volatile(
            "ds_read_b64_tr_b16 %0, %5\n\t"
            "ds_read_b64_tr_b16 %1, %5 offset:512\n\t"
            "ds_read_b64_tr_b16 %2, %5 offset:1024\n\t"
            "ds_read_b64_tr_b16 %3, %5 offset:1536\n\t"
            "ds_read_b64_tr_b16 %4, %5 offset:2048"
            : "=&v"(xq0), "=&v"(xq1), "=&v"(xq2), "=&v"(xq3), "=&v"(xq4)
            : "v"(xrd));

        // gather for p+1: idx is an LDS read -> issues immediately, covered
        // by layer1 + layer2 + softmax (~450 cyc)
        issueB(p + 1 < PTS ? p + 1 : PTS - 1, nxtc);

        // ---- layer 1 (transposed): h^T = W1^T @ X^T, 6 MFMA, no LDS ----
        f32x4 a0 = {0.f, 0.f, 0.f, 0.f};
        f32x4 a1 = {0.f, 0.f, 0.f, 0.f};
        a0 = __builtin_amdgcn_mfma_f32_16x16x32_f16(W1A[0][0], stF0[buf], a0, 0, 0, 0);
        a1 = __builtin_amdgcn_mfma_f32_16x16x32_f16(W1A[1][0], stF0[buf], a1, 0, 0, 0);
        a0 = __builtin_amdgcn_mfma_f32_16x16x32_f16(W1A[0][1], stF1[buf], a0, 0, 0, 0);
        a1 = __builtin_amdgcn_mfma_f32_16x16x32_f16(W1A[1][1], stF1[buf], a1, 0, 0, 0);
        a0 = __builtin_amdgcn_mfma_f32_16x16x32_f16(W1A[0][2], geoF,      a0, 0, 0, 0);
        a1 = __builtin_amdgcn_mfma_f32_16x16x32_f16(W1A[1][2], geoF,      a1, 0, 0, 0);

        // D-frag -> layer-2 A-frag (sigma permutation), bias+relu+cvt only
        half8 A2;
        #pragma unroll
        for (int r = 0; r < 4; ++r) {
            A2[r]     = (_Float16)fmaxf(a0[r] + b1v[r], 0.f);
            A2[4 + r] = (_Float16)fmaxf(a1[r] + b1w[r], 0.f);
        }

        asm volatile("s_waitcnt lgkmcnt(0)" ::: "memory");
        __builtin_amdgcn_sched_barrier(0);       // rule #18: pin tr-read data

        const half4v xqs[5] = { xq0, xq1, xq2, xq3, xq4 };
        const size_t obase = (size_t)n * AGG_LD;

        #pragma unroll
        for (int nt = 0; nt < 5; ++nt) {
            f32x4 acc = {0.f, 0.f, 0.f, 0.f};
            acc = __builtin_amdgcn_mfma_f32_16x16x32_f16(A2, W2B[nt], acc, 0, 0, 0);
            const float bb = b2v[nt];        // (b2-2)*log2e, shift cancels
            // e = exp2(acc+bb) * mask, packed fp16
            half2v ef01 = pk2h(__builtin_amdgcn_exp2f(acc[0] + bb),
                               __builtin_amdgcn_exp2f(acc[1] + bb)) * mk01;
            half2v ef23 = pk2h(__builtin_amdgcn_exp2f(acc[2] + bb),
                               __builtin_amdgcn_exp2f(acc[3] + bb)) * mk23;
            const half2v xlo = { xqs[nt][0], xqs[nt][1] };
            const half2v xhi = { xqs[nt][2], xqs[nt][3] };
            const half2v exf01 = ef01 * xlo;
            const half2v exf23 = ef23 * xhi;
            const half4v ef  = { ef01[0], ef01[1], ef23[0], ef23[1] };
            const half4v exf = { exf01[0], exf01[1], exf23[0], exf23[1] };
            // D-frag == K=16 B-frag: ones-row MFMA -> column sums, no shfl
            f32x4 sden = {0.f, 0.f, 0.f, 0.f};
            f32x4 snum = {0.f, 0.f, 0.f, 0.f};
            sden = __builtin_amdgcn_mfma_f32_16x16x16f16(ones, ef,  sden, 0, 0, 0);
            snum = __builtin_amdgcn_mfma_f32_16x16x16f16(ones, exf, snum, 0, 0, 0);
            const float aggv = snum[0] * __builtin_amdgcn_rcpf(sden[0] + 1e-8f);
            if (val && g == (nt & 3)) aggw[obase + nt * 16 + m] = (_Float16)aggv;
        }
        if (val && lane < 16) aggw[obase + 80 + lane] = (_Float16)0.f;
        // no trailing fence: tr-reads completed at the waitcnt above
    };

    issueB(0, IC<0>{});
    #pragma unroll
    for (int p = 0; p < PTS; p += 2) {
        body(p,     IC<0>{}, IC<1>{});
        body(p + 1, IC<1>{}, IC<0>{});
    }
}

// ================= kernel 2: point MLP + shortcut + xyz passthrough =========
// 512 threads = 8 waves; each wave owns one 16-point tile.
__global__ __launch_bounds__(512) void point_kernel(
    const float* __restrict__ xyz, const _Float16* __restrict__ pts16,
    const _Float16* __restrict__ aggw, const _Float16* __restrict__ ptab,
    float* __restrict__ out, int N, int ntiles)
{
    __shared__ __align__(16) _Float16 sW[PTAB_SZ];   // Wm1t|Wm2t|Wsct|bias
    __shared__ __align__(16) _Float16 sH2[8][16 * 72];

    const int tid = threadIdx.x;

    // fold xyz passthrough copy
    for (int gid = blockIdx.x * 512 + tid; gid < 3 * N; gid += gridDim.x * 512)
        out[gid] = xyz[gid];

    // weight tables: vectorized contiguous copy (2000 x half8)
    {
        const half8* __restrict__ pt8 = (const half8*)ptab;
        half8* __restrict__ sw8 = (half8*)sW;
        #pragma unroll 4
        for (int i = tid; i < PTAB_SZ / 8; i += 512)
            sw8[i] = pt8[i];
    }
    __syncthreads();

    const _Float16* __restrict__ sWm1 = &sW[PW1_OFF];
    const _Float16* __restrict__ sWm2 = &sW[PW2_OFF];
    const _Float16* __restrict__ sWsc = &sW[PSC_OFF];

    const int w = tid >> 6, lane = tid & 63;
    const int m = lane & 15, g = lane >> 4;
    const int t = blockIdx.x * 8 + w;
    if (t >= ntiles) return;          // no barriers after this point
    const int row0 = t * 16;
    _Float16* __restrict__ H2 = sH2[w];

    const int rl = min(row0 + m, N - 1);   // clamped load row

    // ---- m1: h2 = relu(agg[16,96] @ Wm1[96,64]) : 12 MFMA ----
    f32x4 acc[4] = {{0.f,0.f,0.f,0.f},{0.f,0.f,0.f,0.f},
                    {0.f,0.f,0.f,0.f},{0.f,0.f,0.f,0.f}};
    #pragma unroll
    for (int kc = 0; kc < 3; ++kc) {
        const int ko = kc * 32 + g * 8;
        half8 a = *(const half8*)&aggw[(size_t)rl * AGG_LD + ko];
        #pragma unroll
        for (int nt = 0; nt < 4; ++nt) {
            half8 b = *(const half8*)&sWm1[(nt * 16 + m) * X_LD + ko];
            acc[nt] = __builtin_amdgcn_mfma_f32_16x16x32_f16(a, b, acc[nt], 0, 0, 0);
        }
    }
    #pragma unroll
    for (int nt = 0; nt < 4; ++nt) {
        const float bb = (float)sW[PB_OFF + nt * 16 + m];
        #pragma unroll
        for (int r = 0; r < 4; ++r)
            H2[(g * 4 + r) * 72 + nt * 16 + m] = (_Float16)fmaxf(acc[nt][r] + bb, 0.f);
    }
    lgkm_fence();

    // ---- m2 + shortcut: out = h2@Wm2 + pts@Wsc + (bm2+bsc) : 16 MFMA ----
    f32x4 acc2[4] = {{0.f,0.f,0.f,0.f},{0.f,0.f,0.f,0.f},
                     {0.f,0.f,0.f,0.f},{0.f,0.f,0.f,0.f}};
    #pragma unroll
    for (int kc = 0; kc < 2; ++kc) {
        const int ko = kc * 32 + g * 8;
        half8 ah = *(const half8*)&H2[m * 72 + ko];
        half8 ap = *(const half8*)&pts16[(size_t)rl * CIN + ko];
        #pragma unroll
        for (int nt = 0; nt < 4; ++nt) {
            half8 b2f = *(const half8*)&sWm2[(nt * 16 + m) * 72 + ko];
            half8 bsf = *(const half8*)&sWsc[(nt * 16 + m) * 72 + ko];
            acc2[nt] = __builtin_amdgcn_mfma_f32_16x16x32_f16(ah, b2f, acc2[nt], 0, 0, 0);
            acc2[nt] = __builtin_amdgcn_mfma_f32_16x16x32_f16(ap, bsf, acc2[nt], 0, 0, 0);
        }
    }
    float* __restrict__ outp = out + (size_t)3 * N;
    #pragma unroll
    for (int nt = 0; nt < 4; ++nt) {
        const float bb = (float)sW[PB_OFF + 64 + nt * 16 + m];
        #pragma unroll
        for (int r = 0; r < 4; ++r) {
            const int row = row0 + g * 4 + r;
            if (row < N) outp[(size_t)row * MH + nt * 16 + m] = acc2[nt][r] + bb;
        }
    }
}

// ================= fallback: verified R2 fused fp32 kernel ==================
__global__ __launch_bounds__(256) void fused_ip_kernel(
    const float* __restrict__ xyz, const float* __restrict__ xyz_nn,
    const float* __restrict__ points, const int* __restrict__ knn,
    const float* __restrict__ dists, const void* __restrict__ mask,
    const float* __restrict__ w1, const float* __restrict__ b1,
    const float* __restrict__ w2, const float* __restrict__ b2,
    const float* __restrict__ wm1, const float* __restrict__ bm1,
    const float* __restrict__ wm2, const float* __restrict__ bm2,
    const float* __restrict__ wsc, const float* __restrict__ bsc,
    float* __restrict__ out, int N)
{
    __shared__ __align__(16) float gp[4][K][72];
    __shared__ float hb [4][K][33];
    __shared__ float dkb[4][K][69];
    __shared__ float mkb[4][K];
    __shared__ int   sidx[4][K];
    __shared__ float aggb[4][CG];
    __shared__ float h2b[4][MH];
    __shared__ float ptb[4][CIN];

    const int tid  = threadIdx.x;
    const int w    = tid >> 6;
    const int lane = tid & 63;
    {
        int gid = blockIdx.x * 256 + tid;
        if (gid < 3 * N) out[gid] = xyz[gid];
    }
    int n = blockIdx.x * 4 + w;
    const bool valid = (n < N);
    if (!valid) n = 0;
    float* __restrict__ outp = out + (size_t)3 * N;

    if (lane < K) {
        const int idx = knn[n * K + lane];
        sidx[w][lane] = idx;
        const bool mv = mask_is_int32(mask)
            ? (((const int*)mask)[n * K + lane] != 0)
            : (((const uint8_t*)mask)[n * K + lane] != 0);
        mkb[w][lane]  = mv ? 1.0f : 0.0f;
        const float cx = xyz[n * 3 + 0], cy = xyz[n * 3 + 1], cz = xyz[n * 3 + 2];
        gp[w][lane][0] = xyz_nn[idx * 3 + 0] - cx;
        gp[w][lane][1] = xyz_nn[idx * 3 + 1] - cy;
        gp[w][lane][2] = xyz_nn[idx * 3 + 2] - cz;
        gp[w][lane][3] = dists[n * K + lane];
    }
    ptb[w][lane] = points[(size_t)n * CIN + lane];
    __syncthreads();
    for (int k = 0; k < K; ++k) {
        const int idx = sidx[w][k];
        gp[w][k][4 + lane] = points[(size_t)idx * CIN + lane];
    }
    __syncthreads();
    {
        const int j  = lane & 31;
        const int kh = lane >> 5;
        float acc[8];
        const float bj = b1[j];
        #pragma unroll
        for (int kk = 0; kk < 8; ++kk) acc[kk] = bj;
        for (int c4 = 0; c4 < 17; ++c4) {
            float w1v[4];
            #pragma unroll
            for (int i = 0; i < 4; ++i) w1v[i] = w1[(c4 * 4 + i) * HID + j];
            #pragma unroll
            for (int kk = 0; kk < 8; ++kk) {
                const int k = kk * 2 + kh;
                const float4 g4 = *reinterpret_cast<const float4*>(&gp[w][k][c4 * 4]);
                acc[kk] += g4.x * w1v[0] + g4.y * w1v[1] + g4.z * w1v[2] + g4.w * w1v[3];
            }
        }
        #pragma unroll
        for (int kk = 0; kk < 8; ++kk) {
            const int k = kk * 2 + kh;
            hb[w][k][j] = fmaxf(acc[kk], 0.0f);
        }
    }
    __syncthreads();
    {
        const int k = lane >> 2;
        const int q = lane & 3;
        float acc[17];
        #pragma unroll
        for (int i = 0; i < 17; ++i) acc[i] = b2[q * 17 + i];
        for (int j2 = 0; j2 < HID; ++j2) {
            const float hv = hb[w][k][j2];
            const float* __restrict__ w2r = &w2[j2 * CG + q * 17];
            #pragma unroll
            for (int i = 0; i < 17; ++i) acc[i] += hv * w2r[i];
        }
        #pragma unroll
        for (int i = 0; i < 17; ++i) dkb[w][k][q * 17 + i] = acc[i];
    }
    __syncthreads();
    {
        #pragma unroll
        for (int rep = 0; rep < 2; ++rep) {
            const int c = rep * 64 + lane;
            if (c < CG) {
                float v[K];
                float mm = -1e30f;
                #pragma unroll
                for (int k = 0; k < K; ++k) { v[k] = dkb[w][k][c]; mm = fmaxf(mm, v[k]); }
                float s = 0.0f;
                #pragma unroll
                for (int k = 0; k < K; ++k) {
                    const float e = __expf(v[k] - mm) * mkb[w][k];
                    v[k] = e; s += e;
                }
                const float inv = 1.0f / (s + 1e-8f);
                float a = 0.0f;
                #pragma unroll
                for (int k = 0; k < K; ++k) a += v[k] * gp[w][k][c];
                aggb[w][c] = a * inv;
            }
        }
    }
    __syncthreads();
    {
        float acc = bm1[lane];
        for (int c = 0; c < CG; ++c) acc += aggb[w][c] * wm1[c * MH + lane];
        h2b[w][lane] = fmaxf(acc, 0.0f);
    }
    __syncthreads();
    {
        float acc = bm2[lane] + bsc[lane];
        for (int j2 = 0; j2 < MH; ++j2) acc += h2b[w][j2] * wm2[j2 * MH + lane];
        for (int c = 0; c < CIN; ++c)  acc += ptb[w][c] * wsc[c * MH + lane];
        if (valid) outp[(size_t)n * MH + lane] = acc;
    }
}

} // namespace

extern "C" void kernel_launch(void* const* d_in, const int* in_sizes, int n_in,
                              void* d_out, int out_size, void* d_ws, size_t ws_size,
                              hipStream_t stream)
{
    const float*   xyz    = (const float*)d_in[0];
    const float*   xyz_nn = (const float*)d_in[1];
    const float*   points = (const float*)d_in[2];
    const int*     knn    = (const int*)d_in[3];
    const float*   dists  = (const float*)d_in[4];
    const void*    mask   = d_in[5];
    const float*   w1  = (const float*)d_in[6];
    const float*   b1  = (const float*)d_in[7];
    const float*   w2  = (const float*)d_in[8];
    const float*   b2  = (const float*)d_in[9];
    const float*   wm1 = (const float*)d_in[10];
    const float*   bm1 = (const float*)d_in[11];
    const float*   wm2 = (const float*)d_in[12];
    const float*   bm2 = (const float*)d_in[13];
    const float*   wsc = (const float*)d_in[14];
    const float*   bsc = (const float*)d_in[15];

    float* out = (float*)d_out;
    const int N = in_sizes[0] / 3;
    const size_t agg_bytes  = (size_t)N * AGG_LD * sizeof(_Float16);
    const size_t pts_bytes  = (size_t)N * CIN * sizeof(_Float16);
    const size_t ftab_bytes = (size_t)FTAB_SZ * sizeof(_Float16);
    const size_t ptab_bytes = (size_t)PTAB_SZ * sizeof(_Float16);

    if (ws_size >= agg_bytes + pts_bytes + ftab_bytes + ptab_bytes) {
        _Float16* aggw  = (_Float16*)d_ws;
        _Float16* pts16 = (_Float16*)((char*)d_ws + agg_bytes);
        _Float16* ftab  = (_Float16*)((char*)d_ws + agg_bytes + pts_bytes);
        _Float16* ptab  = (_Float16*)((char*)d_ws + agg_bytes + pts_bytes + ftab_bytes);

        hipLaunchKernelGGL(cvt_kernel, dim3(2048), dim3(256), 0, stream,
                           points, pts16, N * CIN / 4,
                           w1, b1, w2, b2, wm1, bm1, wm2, bm2, wsc, bsc,
                           ftab, ptab);

        const int ppb     = 8 * PTS;                 // points per block
        const int blocks1 = (N + ppb - 1) / ppb;
        hipLaunchKernelGGL(edge_kernel, dim3(blocks1), dim3(512), 0, stream,
                           xyz, xyz_nn, pts16, knn, dists, mask,
                           ftab, aggw, N);

        const int ntiles  = (N + 15) / 16;
        const int blocks2 = (ntiles + 7) / 8;
        hipLaunchKernelGGL(point_kernel, dim3(blocks2), dim3(512), 0, stream,
                           xyz, pts16, aggw, ptab, out, N, ntiles);
    } else {
        const int blocks = (N + 3) / 4;
        hipLaunchKernelGGL(fused_ip_kernel, dim3(blocks), dim3(256), 0, stream,
                           xyz, xyz_nn, points, knn, dists, mask,
                           w1, b1, w2, b2, wm1, bm1, wm2, bm2, wsc, bsc,
                           out, N);
    }
}